// Round 6
// baseline (2144.009 us; speedup 1.0000x reference)
//
#include <hip/hip_runtime.h>

// JointBilateralFilter B=16,C=1,H=768,W=1024 fp32, 9x9, sigma_s=2, sigma_r=0.1.
// valid = (sparse != 1.0); constant pad 1.0 => out-of-image taps never contribute
// (reflect-pad of depth is dead code). ~5% valid density.
//
// R6: SCATTER structure. One wave per 16x16 output tile. Scan the clipped
// 24x24 halo (staged as 24x32 float4 rounds); for each valid entry, the 64
// LANES ARE ITS TAPS: lane t -> (dy,dx)=(t/9-4,t%9-4) with spatial log-weight
// and accumulator/depth offsets held as per-lane CONSTANTS. Scatter (w*sv, w)
// into LDS num/den planes with ds_add_f32 (no rmw chain, no box test, no
// spatial math in the loop). Out-of-tile taps land in an 8-wide pad ring
// (adds are harmless, pads never read). 81 taps = 2 rounds (64 + 17-masked).
// Single wave per block => no barriers, no cross-wave races.

#define HH 768
#define WW 1024
#define BB 16
#define CS (-0.18033688011112042f)   /* -log2(e)/8  */
#define CR (-72.13475204444817f)     /* -50*log2(e) */

#define ACC_STRIDE 35                /* 32 rows x 35: bank = (3r+c)%32, ~2-3 way */
#define ACC_PLANE  (32 * ACC_STRIDE) /* 1120 floats per plane */
#define DT_STRIDE  20                /* b128-alignable, (20r+c)%32 ~2-way */
#define DTB        (2 * ACC_PLANE)   /* dtile base index inside lds[] */
/* dtile index excursions: [-168, +483] rel. to DTB; DTB=2240 >= 168 and we
   allocate 484 floats of dtile+tail, so ALL reads stay inside lds[]. */
#define LDS_FLOATS (2 * ACC_PLANE + 484)

__device__ __forceinline__ float rlanef(float v, int b) {
    return __int_as_float(__builtin_amdgcn_readlane(__float_as_int(v), b));
}

__global__ __launch_bounds__(64) void jbf_kernel(
    const float* __restrict__ sparse,
    const float* __restrict__ depth,
    float* __restrict__ out)
{
    __shared__ float lds[LDS_FLOATS];

    const int lane = (int)threadIdx.x;
    const int tx = (int)blockIdx.x << 4;
    const int ty = (int)blockIdx.y << 4;
    const size_t plane = (size_t)blockIdx.z * (size_t)(HH * WW);
    const float* sp = sparse + plane;
    const float* dp = depth  + plane;

    // clipped staging window: 24 rows x 32 cols, inside the image
    const int px0 = min(max(tx - 4, 0), WW - 32);
    const int py0 = min(max(ty - 4, 0), HH - 24);
    const int txoff = tx - px0;                  // 0..16 (4 interior)
    const int tyoff = ty - py0;                  // 0..8  (4 interior)

    // ---- issue ALL global loads upfront (7 float4s) ----
    const int wrow = lane >> 3;                  // 0..7 (+8 per round)
    const int wcolb = (lane & 7) << 2;           // 0,4,...,28
    const float4* spw0 = (const float4*)(sp + (py0 + wrow     ) * WW + px0 + wcolb);
    const float4* spw1 = (const float4*)(sp + (py0 + wrow +  8) * WW + px0 + wcolb);
    const float4* spw2 = (const float4*)(sp + (py0 + wrow + 16) * WW + px0 + wcolb);
    const float4* dpw0 = (const float4*)(dp + (py0 + wrow     ) * WW + px0 + wcolb);
    const float4* dpw1 = (const float4*)(dp + (py0 + wrow +  8) * WW + px0 + wcolb);
    const float4* dpw2 = (const float4*)(dp + (py0 + wrow + 16) * WW + px0 + wcolb);
    const float4 s40 = *spw0, s41 = *spw1, s42 = *spw2;
    const float4 d40 = *dpw0, d41 = *dpw1, d42 = *dpw2;
    const int drow = lane >> 2, dcolb = (lane & 3) << 2;     // depth tile 16x16
    const float4 dt4 = *(const float4*)(dp + (ty + drow) * WW + tx + dcolb);

    // ---- per-lane tap constants (lane = tap index; 81 taps in 2 rounds) ----
    const int t1 = lane + 64;
    const bool act1 = (lane < 17);
    const int dy0 = lane / 9 - 4, dx0 = lane % 9 - 4;
    const int dy1 = t1 / 9 - 4,   dx1 = t1 % 9 - 4;
    const float ls0 = CS * (float)(dy0 * dy0 + dx0 * dx0);
    const float ls1 = CS * (float)(dy1 * dy1 + dx1 * dx1);
    const int voffN0 = dy0 * ACC_STRIDE + dx0;
    const int voffN1 = act1 ? (dy1 * ACC_STRIDE + dx1) : 0;  // inactive -> slot 0 off, w=0
    const int voffD0 = dy0 * DT_STRIDE + dx0;
    const int voffD1 = act1 ? (dy1 * DT_STRIDE + dx1) : 0;

    // ---- zero the 16x16 real accumulator slots (pads may hold garbage) ----
    #pragma unroll
    for (int i = 0; i < 4; ++i) {
        const int id = i * 64 + lane;
        const int slot = ((id >> 4) + 8) * ACC_STRIDE + (id & 15) + 8;
        lds[slot] = 0.0f;
        lds[ACC_PLANE + slot] = 0.0f;
    }

    // ---- stage depth tile (b128-aligned: (drow*20+dcolb)%4==0) ----
    *(float4*)&lds[DTB + drow * DT_STRIDE + dcolb] = dt4;

    // ---- scan + scatter ----
    const int rowrel4_0 = wrow - tyoff + 4;      // per-lane; +8 per round
    const int colrel4b  = wcolb - txoff + 4;     // +k per component

    #pragma unroll
    for (int r = 0; r < 3; ++r) {
        const float4 s4 = (r == 0) ? s40 : (r == 1) ? s41 : s42;
        const float4 d4 = (r == 0) ? d40 : (r == 1) ? d41 : d42;
        const bool vrow = (unsigned)(rowrel4_0 + 8 * r) < 24u;
        #pragma unroll
        for (int k = 0; k < 4; ++k) {
            const float svk = (k == 0) ? s4.x : (k == 1) ? s4.y : (k == 2) ? s4.z : s4.w;
            const float dvk = (k == 0) ? d4.x : (k == 1) ? d4.y : (k == 2) ? d4.z : d4.w;
            const bool vcol = (unsigned)(colrel4b + k) < 24u;
            unsigned long long m = __ballot((svk != 1.0f) & vrow & vcol);
            while (m) {                          // uniform scalar-controlled loop
                const int b = (int)__builtin_ctzll(m);
                m &= (m - 1ull);
                const float sv_e = rlanef(svk, b);
                const float dv_e = rlanef(dvk, b);
                const int erow = 8 * r + (b >> 3);            // SALU
                const int ecol = ((b & 7) << 2) + k;          // SALU
                const int eyrel = erow - tyoff;               // [-4,19]
                const int exrel = ecol - txoff;               // [-4,19]
                const int baseN = (eyrel + 8) * ACC_STRIDE + (exrel + 8);
                const int baseD = DTB + eyrel * DT_STRIDE + exrel;
                // round 0: taps 0..63
                {
                    const float dq = lds[baseD + voffD0];
                    const float diff = dq - dv_e;
                    const float w = __builtin_amdgcn_exp2f(fmaf(diff * CR, diff, ls0));
                    atomicAdd(&lds[baseN + voffN0], w * sv_e);
                    atomicAdd(&lds[ACC_PLANE + baseN + voffN0], w);
                }
                // round 1: taps 64..80 (lanes >=17 forced to w=0, slot offset 0)
                {
                    const float dq = lds[baseD + voffD1];
                    const float diff = dq - dv_e;
                    float w = __builtin_amdgcn_exp2f(fmaf(diff * CR, diff, ls1));
                    w = act1 ? w : 0.0f;         // also kills any NaN from pad reads
                    atomicAdd(&lds[baseN + voffN1], w * sv_e);
                    atomicAdd(&lds[ACC_PLANE + baseN + voffN1], w);
                }
            }
        }
    }

    // ---- writeback (single wave: LDS ops are wave-ordered; compiler waits) ----
    #pragma unroll
    for (int t = 0; t < 4; ++t) {
        const int id = t * 64 + lane;
        const int prow = id >> 4, pcol = id & 15;
        const int slot = (prow + 8) * ACC_STRIDE + pcol + 8;
        const float n = lds[slot];
        const float d = lds[ACC_PLANE + slot];
        float res = n * __builtin_amdgcn_rcpf(d + 1e-8f);
        res = (d < 1e-8f) ? 1.0f : res;
        out[plane + (size_t)(ty + prow) * WW + tx + pcol] = res;
    }
}

extern "C" void kernel_launch(void* const* d_in, const int* in_sizes, int n_in,
                              void* d_out, int out_size, void* d_ws, size_t ws_size,
                              hipStream_t stream)
{
    const float* sparse = (const float*)d_in[0];
    const float* depth  = (const float*)d_in[1];
    float* out = (float*)d_out;
    dim3 grid(WW / 16, HH / 16, BB);   // 64 x 48 x 16 blocks, 1 wave each
    jbf_kernel<<<grid, dim3(64, 1, 1), 0, stream>>>(sparse, depth, out);
}

// Round 7
// 176.004 us; speedup vs baseline: 12.1816x; 12.1816x over previous
//
#include <hip/hip_runtime.h>

// JointBilateralFilter B=16,C=1,H=768,W=1024 fp32, 9x9, sigma_s=2, sigma_r=0.1.
// valid = (sparse != 1.0); constant pad 1.0 => out-of-image taps never contribute
// (reflect-pad of depth is dead code). ~5% valid density.
//
// R7: PIXEL-PACKED gather-scan. Each lane owns TWO pixels (gx, gx+8); wave tile
// 16 wide x 8 tall = 128 px (2x the px per wave => fixed overhead halves per px,
// which R4/R5 showed is ~75% of the cost). All per-entry float math is 2-wide
// ext_vector fp32 => v_pk_{add,mul,fma}_f32 (full-rate packed fp32 on gfx950).
// LDS spatial table T[dy+15][dx+23] = in-box? CS*(dy^2+dx^2) : -1e30 folds the
// box test; slot1 (pixel at gx+8) reads the same row at column-8 => the two
// reads are {tb[8], tb[0]} off one address (ds_read2-mergeable). Entry coords
// are SALU (tile constants readfirstlane'd). Table build: fill -1e30 + write
// only the 81 in-box cells. atomics/scatter abandoned (R6: LDS fp atomicAdd
// => CAS loop => 20x regression).

#define HH 768
#define WW 1024
#define BB 16
#define CS (-0.18033688011112042f)   /* -log2(e)/8  */
#define CR (-72.13475204444817f)     /* -50*log2(e) */

#define TS 48                        /* table row stride (floats): 2-way banks */
#define TROWS 31                     /* dy in [-15,15] */
#define TSIZE (TROWS * TS)           /* 1488 floats = 5952 B */

typedef float f2 __attribute__((ext_vector_type(2)));

__device__ __forceinline__ int rfl(int x) { return __builtin_amdgcn_readfirstlane(x); }
__device__ __forceinline__ float rlanef(float v, int b) {
    return __int_as_float(__builtin_amdgcn_readlane(__float_as_int(v), b));
}
__device__ __forceinline__ f2 splat(float x) { f2 r; r.x = x; r.y = x; return r; }

__global__ __launch_bounds__(256) void jbf_kernel(
    const float* __restrict__ sparse,
    const float* __restrict__ depth,
    float* __restrict__ out)
{
    __shared__ float Tab[TSIZE];
    const int tid  = (int)threadIdx.x;
    const int lane = tid & 63;
    const int wv   = tid >> 6;                    // 4 waves/block, 2x2 tiles

    // ---- table build: fill -1e30, barrier, write the 81 in-box cells ----
    for (int i = tid; i < TSIZE; i += 256) Tab[i] = -1e30f;
    __syncthreads();
    if (tid < 81) {
        const int rr = (tid * 57) >> 9;           // tid/9 for tid<81
        const int cc = tid - 9 * rr;
        const float dy = (float)(rr - 4), dx = (float)(cc - 4);
        Tab[(rr + 11) * TS + cc + 19] = CS * fmaf(dy, dy, dx * dx);
    }
    __syncthreads();

    // ---- wave-uniform tile constants (SGPRs) ----
    const int tx = rfl(((int)blockIdx.x << 5) + ((wv & 1) << 4));   // 16-wide tile
    const int ty = rfl(((int)blockIdx.y << 4) + ((wv >> 1) << 3));  // 8-tall tile
    const int px0 = rfl(min(max(tx - 4, 0), WW - 24));              // 24-col window
    const int py0 = rfl(min(max(ty - 4, 0), HH - 16));              // 16-row window
    const int txoff = tx - px0;                   // 0..8
    const int tyoff = ty - py0;                   // 0..8

    const size_t plane = (size_t)blockIdx.z * (size_t)(HH * WW);
    const float* sp = sparse + plane;
    const float* dp = depth  + plane;

    // ---- stage 16x24 window: 3 float2 per lane per input ----
    const int r  = lane >> 2;                     // 0..15 window row
    const int c0 = (lane & 3) << 1;               // float2 col 0,2,4,6 (+8 per j)
    const float* wbs = sp + (py0 + r) * WW + px0 + c0;
    const float* wbd = dp + (py0 + r) * WW + px0 + c0;
    const f2 s20 = *(const f2*)(wbs);
    const f2 s21 = *(const f2*)(wbs + 8);
    const f2 s22 = *(const f2*)(wbs + 16);
    const f2 d20 = *(const f2*)(wbd);
    const f2 d21 = *(const f2*)(wbd + 8);
    const f2 d22 = *(const f2*)(wbd + 16);

    // ---- per-lane pixel pair (gx, gx+8) ----
    const int my = lane >> 3, mx = lane & 7;
    const int gy = ty + my, gx = tx + mx;
    const float myd0 = dp[gy * WW + gx];
    const float myd1 = dp[gy * WW + gx + 8];
    f2 nmyd; nmyd.x = -myd0; nmyd.y = -myd1;
    const int clane_w = my * TS + mx;             // per-lane table float offset

    f2 numA = splat(0.0f), denA = splat(0.0f);
    f2 numB = splat(0.0f), denB = splat(0.0f);
    const f2 crp = splat(CR);

    // SALU base: 48*(dy+15) + (dx0+23) - 8 decomposition (lane part = clane_w)
    const int sbase0 = TS * (15 - tyoff) + (23 - txoff) - 8;

    #pragma unroll
    for (int j = 0; j < 3; ++j) {
        const f2 s2 = (j == 0) ? s20 : (j == 1) ? s21 : s22;
        const f2 d2 = (j == 0) ? d20 : (j == 1) ? d21 : d22;
        #pragma unroll
        for (int k = 0; k < 2; ++k) {
            const float svk = k ? s2.y : s2.x;
            const float dvk = k ? d2.y : d2.x;
            const int sbase = sbase0 + 8 * j + k;          // SALU
            unsigned long long m = __ballot(svk != 1.0f);
            while (m) {                                     // uniform scalar loop
                const int b0 = (int)__builtin_ctzll(m);
                m &= (m - 1ull);
                {
                    const float sv_e = rlanef(svk, b0);
                    const float dv_e = rlanef(dvk, b0);
                    const int SW = sbase + (b0 >> 2) * TS + ((b0 & 3) << 1); // SALU
                    const float* tb = Tab + (SW - clane_w); // one v_sub
                    f2 tp; tp.x = tb[8]; tp.y = tb[0];      // ds_read2_b32
                    const f2 diff = nmyd + splat(dv_e);
                    const f2 q = diff * crp;
                    const f2 arg = q * diff + tp;           // pk_fma
                    f2 w; w.x = __builtin_amdgcn_exp2f(arg.x);
                    w.y = __builtin_amdgcn_exp2f(arg.y);
                    denA += w;
                    numA += w * splat(sv_e);                // pk_fma
                }
                if (m) {                                    // independent B chain
                    const int b1 = (int)__builtin_ctzll(m);
                    m &= (m - 1ull);
                    const float sv_e = rlanef(svk, b1);
                    const float dv_e = rlanef(dvk, b1);
                    const int SW = sbase + (b1 >> 2) * TS + ((b1 & 3) << 1);
                    const float* tb = Tab + (SW - clane_w);
                    f2 tp; tp.x = tb[8]; tp.y = tb[0];
                    const f2 diff = nmyd + splat(dv_e);
                    const f2 q = diff * crp;
                    const f2 arg = q * diff + tp;
                    f2 w; w.x = __builtin_amdgcn_exp2f(arg.x);
                    w.y = __builtin_amdgcn_exp2f(arg.y);
                    denB += w;
                    numB += w * splat(sv_e);
                }
            }
        }
    }

    const float n0 = numA.x + numB.x, n1 = numA.y + numB.y;
    const float e0 = denA.x + denB.x, e1 = denA.y + denB.y;
    float r0 = n0 * __builtin_amdgcn_rcpf(e0 + 1e-8f);
    r0 = (e0 < 1e-8f) ? 1.0f : r0;
    float r1 = n1 * __builtin_amdgcn_rcpf(e1 + 1e-8f);
    r1 = (e1 < 1e-8f) ? 1.0f : r1;
    float* op = out + plane + (size_t)gy * WW + gx;
    op[0] = r0;
    op[8] = r1;
}

extern "C" void kernel_launch(void* const* d_in, const int* in_sizes, int n_in,
                              void* d_out, int out_size, void* d_ws, size_t ws_size,
                              hipStream_t stream)
{
    const float* sparse = (const float*)d_in[0];
    const float* depth  = (const float*)d_in[1];
    float* out = (float*)d_out;
    dim3 grid(WW / 32, HH / 16, BB);   // 32 x 48 x 16 blocks, 4 waves each
    jbf_kernel<<<grid, dim3(256, 1, 1), 0, stream>>>(sparse, depth, out);
}